// Round 7
// baseline (994.035 us; speedup 1.0000x reference)
//
#include <hip/hip_runtime.h>

#define HH 512
#define WW 512
#define NIMG 12
#define RAD 3
#define TW 64
#define RPW 8             // output rows per block (= per wave; 1 wave/block)
#define LW (TW + 2*RAD)   // 70
#define LH (RPW + 2*RAD)  // 14

// One side-window-filter iteration.
//
// NUMERICS CONTRACT (established R1-R5):
//  - Grading ref is an fp32 replay; conv = sequential fma over the 7x7
//    window in (ky,kx) row-major order, one accumulator (R4: bit-exact).
//  - IM chains determine argmin + dm -> must keep that exact order.
//  - PERT is selection-independent -> quadrant decomposition with row
//    partials hl=(b0+b1)+(b2+b3), hr=(b3+b4)+(b5+b6) (R5/R6: 9.77e-4).
//
// PERF (R6 post-mortem): ring structure good (VALU issue ~17us/dispatch,
// pk_fma-packed) but occupancy collapsed (1536 blocks = 6/CU, VGPR 128 ->
// 16 waves/CU, measured 17% occ -> 26us/dispatch of latency stall).
// This version: ONE WAVE PER BLOCK, 64x8 slab, 6144 blocks = 24/CU.
// No cross-wave barriers, 7.8KB LDS/block; same register rings.
__global__ __launch_bounds__(64, 4) void swf_step(
    const float* __restrict__ im_in, const float* __restrict__ pe_in,
    float* __restrict__ im_out, float* __restrict__ pe_out)
{
    __shared__ float sI[LH][LW];
    __shared__ float sP[LH][LW];

    const int tx = threadIdx.x;        // 0..63, lane == column
    const int x0 = blockIdx.x * TW;
    const int y0 = blockIdx.y * RPW;
    const size_t base = (size_t)blockIdx.z * (size_t)(HH * WW);
    const float* imb = im_in + base;
    const float* peb = pe_in + base;

    // Stage 14 rows x 70 cols (+halo, zero-padded) into LDS
    for (int i = tx; i < LH * LW; i += 64) {
        int r = i / LW;
        int c = i - r * LW;
        int gy = y0 - RAD + r;
        int gx = x0 - RAD + c;
        bool ok = ((unsigned)gy < (unsigned)HH) && ((unsigned)gx < (unsigned)WW);
        int gi = gy * WW + gx;
        sI[r][c] = ok ? imb[gi] : 0.0f;
        sP[r][c] = ok ? peb[gi] : 0.0f;
    }
    __syncthreads();   // single-wave block: compiles to a cheap waitcnt

    const float w28 = 1.0f / 28.0f;   // fp32-rounded, as in the ref's kernels
    const float w16 = 0.0625f;        // exact

    // Phase-rotated register rings; slot for raw row m is m%7.
    float wi[7][7];                   // im taps: wi[m%7][dx] = sI[m][tx+dx]
    float hl[7], hr[7], cc[7];        // pert row partials + center column

    #pragma unroll
    for (int m = 0; m < 7; ++m) {
        #pragma unroll
        for (int dx = 0; dx < 7; ++dx)
            wi[m][dx] = sI[m][tx + dx];
        float b0 = sP[m][tx],     b1 = sP[m][tx + 1], b2 = sP[m][tx + 2],
              b3 = sP[m][tx + 3], b4 = sP[m][tx + 4], b5 = sP[m][tx + 5],
              b6 = sP[m][tx + 6];
        hl[m] = (b0 + b1) + (b2 + b3);
        hr[m] = (b3 + b4) + (b5 + b6);
        cc[m] = b3;
    }

    #pragma unroll
    for (int jj = 0; jj < RPW; ++jj) {
        // ---- im: 8 exact sequential fma chains, window rows dy=0..6 in
        //      slot (jj+dy)%7, row-major tap order within each chain ----
        float d[8];
        {
            float sL = 0.f, sR = 0.f, sU = 0.f, sD = 0.f;
            float sNW = 0.f, sNE = 0.f, sSW = 0.f, sSE = 0.f;
            #pragma unroll
            for (int dy = 0; dy < 7; ++dy) {
                const int s = (jj + dy) % 7;
                #pragma unroll
                for (int dx = 0; dx < 4; ++dx)       // cols x-3..x
                    sL = fmaf(wi[s][dx], w28, sL);
                #pragma unroll
                for (int dx = 3; dx < 7; ++dx)       // cols x..x+3
                    sR = fmaf(wi[s][dx], w28, sR);
            }
            #pragma unroll
            for (int dy = 0; dy < 4; ++dy) {         // rows y-3..y
                const int s = (jj + dy) % 7;
                #pragma unroll
                for (int dx = 0; dx < 7; ++dx)
                    sU = fmaf(wi[s][dx], w28, sU);
                #pragma unroll
                for (int dx = 0; dx < 4; ++dx)
                    sNW = fmaf(wi[s][dx], w16, sNW);
                #pragma unroll
                for (int dx = 3; dx < 7; ++dx)
                    sNE = fmaf(wi[s][dx], w16, sNE);
            }
            #pragma unroll
            for (int dy = 3; dy < 7; ++dy) {         // rows y..y+3
                const int s = (jj + dy) % 7;
                #pragma unroll
                for (int dx = 0; dx < 7; ++dx)
                    sD = fmaf(wi[s][dx], w28, sD);
                #pragma unroll
                for (int dx = 0; dx < 4; ++dx)
                    sSW = fmaf(wi[s][dx], w16, sSW);
                #pragma unroll
                for (int dx = 3; dx < 7; ++dx)
                    sSE = fmaf(wi[s][dx], w16, sSE);
            }
            const float cI = wi[(jj + 3) % 7][3];
            d[0] = sL - cI;  d[1] = sR - cI;  d[2] = sU - cI;  d[3] = sD - cI;
            d[4] = sNW - cI; d[5] = sNE - cI; d[6] = sSW - cI; d[7] = sSE - cI;
        }

        // ---- pert: quadrant decomposition from register rings
        //      (bit-identical formulas to R5/R6) ----
        float e[8];
        const int p0 = (jj + 0) % 7, p1 = (jj + 1) % 7, p2 = (jj + 2) % 7,
                  p3 = (jj + 3) % 7, p4 = (jj + 4) % 7, p5 = (jj + 5) % 7,
                  p6 = (jj + 6) % 7;
        {
            float qnw = ((hl[p0] + hl[p1]) + (hl[p2] + hl[p3]));
            float qsw = ((hl[p3] + hl[p4]) + (hl[p5] + hl[p6]));
            float qne = ((hr[p0] + hr[p1]) + (hr[p2] + hr[p3]));
            float qse = ((hr[p3] + hr[p4]) + (hr[p5] + hr[p6]));
            float cu  = ((cc[p0] + cc[p1]) + (cc[p2] + cc[p3]));
            float cd  = ((cc[p3] + cc[p4]) + (cc[p5] + cc[p6]));
            float cP  = cc[p3];
            e[0] = (qnw + qsw - hl[p3]) * w28 - cP;   // L
            e[1] = (qne + qse - hr[p3]) * w28 - cP;   // R
            e[2] = (qnw + qne - cu)     * w28 - cP;   // U
            e[3] = (qsw + qse - cd)     * w28 - cP;   // D
            e[4] = qnw * w16 - cP;                    // NW
            e[5] = qne * w16 - cP;                    // NE
            e[6] = qsw * w16 - cP;                    // SW
            e[7] = qse * w16 - cP;                    // SE
        }

        // first-index-wins argmin over |d| (jnp.argmin tie-break)
        float bestAbs = fabsf(d[0]);
        float bd = d[0];
        float be = e[0];
        #pragma unroll
        for (int j = 1; j < 8; ++j) {
            float a = fabsf(d[j]);
            bool take = a < bestAbs;
            bestAbs = take ? a : bestAbs;
            bd = take ? d[j] : bd;
            be = take ? e[j] : be;
        }

        const int gy = y0 + jj;
        const int gx = x0 + tx;
        const size_t gi = base + (size_t)gy * WW + gx;
        im_out[gi] = wi[(jj + 3) % 7][3] + bd;   // bit-exact im chain
        pe_out[gi] = cc[p3] + be;                // pert: same drift as R5/R6

        // slide: load raw row jj+7 into slot jj%7 (== jj for jj<7)
        if (jj < RPW - 1) {
            const int m = jj + 7;
            const int slot = jj % 7;
            #pragma unroll
            for (int dx = 0; dx < 7; ++dx)
                wi[slot][dx] = sI[m][tx + dx];
            float b0 = sP[m][tx],     b1 = sP[m][tx + 1], b2 = sP[m][tx + 2],
                  b3 = sP[m][tx + 3], b4 = sP[m][tx + 4], b5 = sP[m][tx + 5],
                  b6 = sP[m][tx + 6];
            hl[slot] = (b0 + b1) + (b2 + b3);
            hr[slot] = (b3 + b4) + (b5 + b6);
            cc[slot] = b3;
        }
    }
}

extern "C" void kernel_launch(void* const* d_in, const int* in_sizes, int n_in,
                              void* d_out, int out_size, void* d_ws, size_t ws_size,
                              hipStream_t stream) {
    const float* im0 = (const float*)d_in[0];
    const float* pe0 = (const float*)d_in[1];
    float* out = (float*)d_out;

    const size_t npix = (size_t)NIMG * HH * WW;   // 3,145,728
    float* imA = (float*)d_ws;                    // 12.6 MB
    float* imB = imA + npix;                      // 12.6 MB
    float* peA = imB + npix;                      // 12.6 MB (ws total 37.7 MB)
    float* peB = out;  // d_out doubles as the second pert buffer; iteration
                       // parity lands the final (iter-5) pert write in d_out.

    dim3 grid(WW / TW, HH / RPW, NIMG);           // 8 x 64 x 12 = 6144 blocks
    dim3 block(64);                               // one wave per block

    swf_step<<<grid, block, 0, stream>>>(im0, pe0, imA, peA);  // iter 0
    swf_step<<<grid, block, 0, stream>>>(imA, peA, imB, peB);  // iter 1
    swf_step<<<grid, block, 0, stream>>>(imB, peB, imA, peA);  // iter 2
    swf_step<<<grid, block, 0, stream>>>(imA, peA, imB, peB);  // iter 3
    swf_step<<<grid, block, 0, stream>>>(imB, peB, imA, peA);  // iter 4
    swf_step<<<grid, block, 0, stream>>>(imA, peA, imB, out);  // iter 5
}

// Round 8
// 241.597 us; speedup vs baseline: 4.1144x; 4.1144x over previous
//
#include <hip/hip_runtime.h>

#define HH 512
#define WW 512
#define NIMG 12
#define RAD 3
#define TW 64
#define TH 16
#define LW (TW + 2*RAD)   // 70
#define LH (TH + 2*RAD)   // 22
#define RPW 4             // consecutive output rows per wave (TH / 4 waves)

// One side-window-filter iteration.
//
// NUMERICS CONTRACT (established R1-R5):
//  - Grading ref is an fp32 replay; conv = sequential fma over the 7x7
//    window in (ky,kx) row-major order, one accumulator (R4: bit-exact).
//  - IM chains determine argmin + dm -> must keep that exact order.
//  - PERT is selection-independent -> quadrant decomposition with row
//    partials hl=(b0+b1)+(b2+b3), hr=(b3+b4)+(b5+b6) (R5/R6: 9.77e-4).
//
// PERF HISTORY:
//  R5 (this launch shape, no ring): 40.2us/dispatch, LDS-pipe-saturated
//     (~83 LDS-b32 ops/output ~= 38us/dispatch of LDS pipe).
//  R6 (ring RPW=8, TH=32, grid 1536): VGPR 128, occupancy collapse, 42.9us.
//  R7 (one-wave blocks, grid 6144): cache locality destroyed, FETCH 23->219MB,
//     4x regression. 256-thread blocks + ~2048-block grid are load-bearing.
//  This round: R5 launch shape + RPW=4 register ring -> ~40 LDS ops/output.
__global__ __launch_bounds__(256) void swf_step(
    const float* __restrict__ im_in, const float* __restrict__ pe_in,
    float* __restrict__ im_out, float* __restrict__ pe_out)
{
    __shared__ float sI[LH][LW];
    __shared__ float sP[LH][LW];

    const int tid = threadIdx.x;
    const int x0 = blockIdx.x * TW;
    const int y0 = blockIdx.y * TH;
    const size_t base = (size_t)blockIdx.z * (size_t)(HH * WW);
    const float* imb = im_in + base;
    const float* peb = pe_in + base;

    // Stage raw tiles + halo(3) into LDS, zero padding outside image
    for (int i = tid; i < LH * LW; i += 256) {
        int r = i / LW;
        int c = i - r * LW;
        int gy = y0 - RAD + r;
        int gx = x0 - RAD + c;
        bool ok = ((unsigned)gy < (unsigned)HH) && ((unsigned)gx < (unsigned)WW);
        int gi = gy * WW + gx;
        sI[r][c] = ok ? imb[gi] : 0.0f;
        sP[r][c] = ok ? peb[gi] : 0.0f;
    }
    __syncthreads();

    const float w28 = 1.0f / 28.0f;   // fp32-rounded, as in the ref's kernels
    const float w16 = 0.0625f;        // exact
    const int tx = tid & 63;
    const int wv = tid >> 6;          // wave id 0..3
    const int r0 = wv * RPW;          // wave's slab: sI rows r0 .. r0+RPW+5

    // Phase-rotated register rings; slot for raw row m is m%7.
    float wi[7][7];                   // im taps: wi[m%7][dx] = sI[r0+m][tx+dx]
    float hl[7], hr[7], cc[7];        // pert row partials + center column

    #pragma unroll
    for (int m = 0; m < 7; ++m) {
        #pragma unroll
        for (int dx = 0; dx < 7; ++dx)
            wi[m][dx] = sI[r0 + m][tx + dx];
        float b0 = sP[r0 + m][tx],     b1 = sP[r0 + m][tx + 1],
              b2 = sP[r0 + m][tx + 2], b3 = sP[r0 + m][tx + 3],
              b4 = sP[r0 + m][tx + 4], b5 = sP[r0 + m][tx + 5],
              b6 = sP[r0 + m][tx + 6];
        hl[m] = (b0 + b1) + (b2 + b3);
        hr[m] = (b3 + b4) + (b5 + b6);
        cc[m] = b3;
    }

    #pragma unroll
    for (int jj = 0; jj < RPW; ++jj) {
        // ---- im: 8 exact sequential fma chains, window rows dy=0..6 in
        //      slot (jj+dy)%7, row-major tap order within each chain ----
        float d[8];
        {
            float sL = 0.f, sR = 0.f, sU = 0.f, sD = 0.f;
            float sNW = 0.f, sNE = 0.f, sSW = 0.f, sSE = 0.f;
            #pragma unroll
            for (int dy = 0; dy < 7; ++dy) {
                const int s = (jj + dy) % 7;
                #pragma unroll
                for (int dx = 0; dx < 4; ++dx)       // cols x-3..x
                    sL = fmaf(wi[s][dx], w28, sL);
                #pragma unroll
                for (int dx = 3; dx < 7; ++dx)       // cols x..x+3
                    sR = fmaf(wi[s][dx], w28, sR);
            }
            #pragma unroll
            for (int dy = 0; dy < 4; ++dy) {         // rows y-3..y
                const int s = (jj + dy) % 7;
                #pragma unroll
                for (int dx = 0; dx < 7; ++dx)
                    sU = fmaf(wi[s][dx], w28, sU);
                #pragma unroll
                for (int dx = 0; dx < 4; ++dx)
                    sNW = fmaf(wi[s][dx], w16, sNW);
                #pragma unroll
                for (int dx = 3; dx < 7; ++dx)
                    sNE = fmaf(wi[s][dx], w16, sNE);
            }
            #pragma unroll
            for (int dy = 3; dy < 7; ++dy) {         // rows y..y+3
                const int s = (jj + dy) % 7;
                #pragma unroll
                for (int dx = 0; dx < 7; ++dx)
                    sD = fmaf(wi[s][dx], w28, sD);
                #pragma unroll
                for (int dx = 0; dx < 4; ++dx)
                    sSW = fmaf(wi[s][dx], w16, sSW);
                #pragma unroll
                for (int dx = 3; dx < 7; ++dx)
                    sSE = fmaf(wi[s][dx], w16, sSE);
            }
            const float cI = wi[(jj + 3) % 7][3];
            d[0] = sL - cI;  d[1] = sR - cI;  d[2] = sU - cI;  d[3] = sD - cI;
            d[4] = sNW - cI; d[5] = sNE - cI; d[6] = sSW - cI; d[7] = sSE - cI;
        }

        // ---- pert: quadrant decomposition from register rings
        //      (bit-identical formulas to R5/R6) ----
        float e[8];
        const int p0 = (jj + 0) % 7, p1 = (jj + 1) % 7, p2 = (jj + 2) % 7,
                  p3 = (jj + 3) % 7, p4 = (jj + 4) % 7, p5 = (jj + 5) % 7,
                  p6 = (jj + 6) % 7;
        {
            float qnw = ((hl[p0] + hl[p1]) + (hl[p2] + hl[p3]));
            float qsw = ((hl[p3] + hl[p4]) + (hl[p5] + hl[p6]));
            float qne = ((hr[p0] + hr[p1]) + (hr[p2] + hr[p3]));
            float qse = ((hr[p3] + hr[p4]) + (hr[p5] + hr[p6]));
            float cu  = ((cc[p0] + cc[p1]) + (cc[p2] + cc[p3]));
            float cd  = ((cc[p3] + cc[p4]) + (cc[p5] + cc[p6]));
            float cP  = cc[p3];
            e[0] = (qnw + qsw - hl[p3]) * w28 - cP;   // L
            e[1] = (qne + qse - hr[p3]) * w28 - cP;   // R
            e[2] = (qnw + qne - cu)     * w28 - cP;   // U
            e[3] = (qsw + qse - cd)     * w28 - cP;   // D
            e[4] = qnw * w16 - cP;                    // NW
            e[5] = qne * w16 - cP;                    // NE
            e[6] = qsw * w16 - cP;                    // SW
            e[7] = qse * w16 - cP;                    // SE
        }

        // first-index-wins argmin over |d| (jnp.argmin tie-break)
        float bestAbs = fabsf(d[0]);
        float bd = d[0];
        float be = e[0];
        #pragma unroll
        for (int j = 1; j < 8; ++j) {
            float a = fabsf(d[j]);
            bool take = a < bestAbs;
            bestAbs = take ? a : bestAbs;
            bd = take ? d[j] : bd;
            be = take ? e[j] : be;
        }

        const int gy = y0 + r0 + jj;
        const int gx = x0 + tx;
        const size_t gi = base + (size_t)gy * WW + gx;
        im_out[gi] = wi[(jj + 3) % 7][3] + bd;   // bit-exact im chain
        pe_out[gi] = cc[p3] + be;                // pert: same drift as R5/R6

        // slide: load raw row r0+jj+7 into slot jj%7 (overwrite oldest)
        if (jj < RPW - 1) {
            const int m = r0 + jj + 7;
            const int slot = jj % 7;
            #pragma unroll
            for (int dx = 0; dx < 7; ++dx)
                wi[slot][dx] = sI[m][tx + dx];
            float b0 = sP[m][tx],     b1 = sP[m][tx + 1], b2 = sP[m][tx + 2],
                  b3 = sP[m][tx + 3], b4 = sP[m][tx + 4], b5 = sP[m][tx + 5],
                  b6 = sP[m][tx + 6];
            hl[slot] = (b0 + b1) + (b2 + b3);
            hr[slot] = (b3 + b4) + (b5 + b6);
            cc[slot] = b3;
        }
    }
}

extern "C" void kernel_launch(void* const* d_in, const int* in_sizes, int n_in,
                              void* d_out, int out_size, void* d_ws, size_t ws_size,
                              hipStream_t stream) {
    const float* im0 = (const float*)d_in[0];
    const float* pe0 = (const float*)d_in[1];
    float* out = (float*)d_out;

    const size_t npix = (size_t)NIMG * HH * WW;   // 3,145,728
    float* imA = (float*)d_ws;                    // 12.6 MB
    float* imB = imA + npix;                      // 12.6 MB
    float* peA = imB + npix;                      // 12.6 MB (ws total 37.7 MB)
    float* peB = out;  // d_out doubles as the second pert buffer; iteration
                       // parity lands the final (iter-5) pert write in d_out.

    dim3 grid(WW / TW, HH / TH, NIMG);            // 8 x 32 x 12 = 3072... no:
    // 512/64=8, 512/16=32 -> 8*32*12 = 3072 blocks; 12 blocks/CU available.
    dim3 block(256);

    swf_step<<<grid, block, 0, stream>>>(im0, pe0, imA, peA);  // iter 0
    swf_step<<<grid, block, 0, stream>>>(imA, peA, imB, peB);  // iter 1
    swf_step<<<grid, block, 0, stream>>>(imB, peB, imA, peA);  // iter 2
    swf_step<<<grid, block, 0, stream>>>(imA, peA, imB, peB);  // iter 3
    swf_step<<<grid, block, 0, stream>>>(imB, peB, imA, peA);  // iter 4
    swf_step<<<grid, block, 0, stream>>>(imA, peA, imB, out);  // iter 5
}

// Round 9
// 235.000 us; speedup vs baseline: 4.2299x; 1.0281x over previous
//
#include <hip/hip_runtime.h>

#define HH 512
#define WW 512
#define NIMG 12
#define RAD 3
#define TW 64
#define TH 16
#define LW (TW + 2*RAD)   // 70
#define LH (TH + 2*RAD)   // 22
#define RPW 4             // consecutive output rows per wave (TH / 4 waves)

typedef float v2 __attribute__((ext_vector_type(2)));

// One side-window-filter iteration.
//
// NUMERICS CONTRACT (established R1-R5):
//  - Grading ref is an fp32 replay; conv = sequential fma over the 7x7
//    window in (ky,kx) row-major order, one accumulator (R4: bit-exact).
//  - IM chains determine argmin + dm -> must keep that exact per-chain order.
//    Here chains are PAIRED into v_pk_fma_f32 lanes (L,R)(U,D)(NW,NE)(SW,SE);
//    each lane's sequence is unchanged -> still bit-exact.
//  - PERT is selection-independent -> quadrant decomposition, formulas
//    bit-identical to R5 (absmax 9.77e-4, passes).
//
// PERF MODEL (revised R8 post-mortem):
//  - NOT LDS-bound: halving LDS ops (R5->R8) changed nothing.
//  - VALU-bound + fixed cost: R4->R5 VALU cut gave exactly proportional
//    gain. Dispatch ~= VALU(~20us) + fixed(~20us: mem round trip, launch,
//    tail). This round halves the fma issue via packed math.
//  - Launch shape 256-thr blocks / 3072-block grid is load-bearing (R7:
//    one-wave blocks destroyed cache locality, FETCH 23->219MB, 4x slower).
__global__ __launch_bounds__(256) void swf_step(
    const float* __restrict__ im_in, const float* __restrict__ pe_in,
    float* __restrict__ im_out, float* __restrict__ pe_out)
{
    __shared__ float sI[LH][LW];
    __shared__ float sP[LH][LW];

    const int tid = threadIdx.x;
    const int x0 = blockIdx.x * TW;
    const int y0 = blockIdx.y * TH;
    const size_t base = (size_t)blockIdx.z * (size_t)(HH * WW);
    const float* imb = im_in + base;
    const float* peb = pe_in + base;

    // Stage raw tiles + halo(3) into LDS, zero padding outside image
    for (int i = tid; i < LH * LW; i += 256) {
        int r = i / LW;
        int c = i - r * LW;
        int gy = y0 - RAD + r;
        int gx = x0 - RAD + c;
        bool ok = ((unsigned)gy < (unsigned)HH) && ((unsigned)gx < (unsigned)WW);
        int gi = gy * WW + gx;
        sI[r][c] = ok ? imb[gi] : 0.0f;
        sP[r][c] = ok ? peb[gi] : 0.0f;
    }
    __syncthreads();

    const float w28 = 1.0f / 28.0f;   // fp32-rounded, as in the ref's kernels
    const float w16 = 0.0625f;        // exact
    const v2 w28v = {w28, w28};
    const v2 w16v = {w16, w16};
    const int tx = tid & 63;
    const int wv = tid >> 6;          // wave id 0..3
    const int r0 = wv * RPW;          // wave's slab: sI rows r0 .. r0+RPW+5

    // Phase-rotated register rings; slot for raw row m is m%7.
    float wi[7][7];                   // im taps: wi[m%7][dx] = sI[r0+m][tx+dx]
    v2    hlr[7];                     // pert row partials {hl, hr}
    float cc[7];                      // pert center column

    #pragma unroll
    for (int m = 0; m < 7; ++m) {
        #pragma unroll
        for (int dx = 0; dx < 7; ++dx)
            wi[m][dx] = sI[r0 + m][tx + dx];
        float b0 = sP[r0 + m][tx],     b1 = sP[r0 + m][tx + 1],
              b2 = sP[r0 + m][tx + 2], b3 = sP[r0 + m][tx + 3],
              b4 = sP[r0 + m][tx + 4], b5 = sP[r0 + m][tx + 5],
              b6 = sP[r0 + m][tx + 6];
        hlr[m] = (v2){(b0 + b1) + (b2 + b3), (b3 + b4) + (b5 + b6)};
        cc[m] = b3;
    }

    #pragma unroll
    for (int jj = 0; jj < RPW; ++jj) {
        // ---- im: 4 packed chains, each lane an exact sequential row-major
        //      fma chain. LR: dy 0..6; UD/quadrants: split at row 3. ----
        v2 aLR = {0.f, 0.f};   // (L, R)
        v2 aUD = {0.f, 0.f};   // (U, D)
        v2 aQN = {0.f, 0.f};   // (NW, NE)
        v2 aQS = {0.f, 0.f};   // (SW, SE)
        #pragma unroll
        for (int dy = 0; dy < 7; ++dy) {
            const int s = (jj + dy) % 7;
            #pragma unroll
            for (int dx = 0; dx < 4; ++dx)   // L: cols 0..3 | R: cols 3..6
                aLR = __builtin_elementwise_fma(
                    (v2){wi[s][dx], wi[s][dx + 3]}, w28v, aLR);
        }
        #pragma unroll
        for (int dy = 0; dy < 4; ++dy) {     // U rows 0..3 | D rows 3..6
            const int su = (jj + dy) % 7;
            const int sd = (jj + dy + 3) % 7;
            #pragma unroll
            for (int dx = 0; dx < 7; ++dx)
                aUD = __builtin_elementwise_fma(
                    (v2){wi[su][dx], wi[sd][dx]}, w28v, aUD);
            #pragma unroll
            for (int dx = 0; dx < 4; ++dx) { // NW/NE from top rows, SW/SE bottom
                aQN = __builtin_elementwise_fma(
                    (v2){wi[su][dx], wi[su][dx + 3]}, w16v, aQN);
                aQS = __builtin_elementwise_fma(
                    (v2){wi[sd][dx], wi[sd][dx + 3]}, w16v, aQS);
            }
        }

        const float cI = wi[(jj + 3) % 7][3];
        const v2 cI2 = {cI, cI};
        const v2 d01 = aLR - cI2;
        const v2 d23 = aUD - cI2;
        const v2 d45 = aQN - cI2;
        const v2 d67 = aQS - cI2;
        float d[8] = {d01.x, d01.y, d23.x, d23.y, d45.x, d45.y, d67.x, d67.y};

        // ---- pert: packed quadrant decomposition (values identical R5) ----
        float e[8];
        const int p0 = (jj + 0) % 7, p1 = (jj + 1) % 7, p2 = (jj + 2) % 7,
                  p3 = (jj + 3) % 7, p4 = (jj + 4) % 7, p5 = (jj + 5) % 7,
                  p6 = (jj + 6) % 7;
        const float cP = cc[p3];
        {
            v2 qN = ((hlr[p0] + hlr[p1]) + (hlr[p2] + hlr[p3])); // (qnw,qne)
            v2 qS = ((hlr[p3] + hlr[p4]) + (hlr[p5] + hlr[p6])); // (qsw,qse)
            float cu = ((cc[p0] + cc[p1]) + (cc[p2] + cc[p3]));
            float cd = ((cc[p3] + cc[p4]) + (cc[p5] + cc[p6]));
            const v2 cP2 = {cP, cP};
            v2 eLR = (qN + qS - hlr[p3]) * w28v - cP2;   // (L, R)
            v2 eQN = qN * w16v - cP2;                    // (NW, NE)
            v2 eQS = qS * w16v - cP2;                    // (SW, SE)
            e[0] = eLR.x;  e[1] = eLR.y;
            e[2] = (qN.x + qN.y - cu) * w28 - cP;        // U
            e[3] = (qS.x + qS.y - cd) * w28 - cP;        // D
            e[4] = eQN.x;  e[5] = eQN.y;
            e[6] = eQS.x;  e[7] = eQS.y;
        }

        // first-index-wins argmin over |d| (jnp.argmin tie-break)
        float bestAbs = fabsf(d[0]);
        float bd = d[0];
        float be = e[0];
        #pragma unroll
        for (int j = 1; j < 8; ++j) {
            float a = fabsf(d[j]);
            bool take = a < bestAbs;
            bestAbs = take ? a : bestAbs;
            bd = take ? d[j] : bd;
            be = take ? e[j] : be;
        }

        const int gy = y0 + r0 + jj;
        const int gx = x0 + tx;
        const size_t gi = base + (size_t)gy * WW + gx;
        im_out[gi] = cI + bd;       // bit-exact im chain
        pe_out[gi] = cP + be;       // pert: same drift as R5/R8

        // slide: load raw row r0+jj+7 into slot jj%7 (overwrite oldest)
        if (jj < RPW - 1) {
            const int m = r0 + jj + 7;
            const int slot = jj % 7;
            #pragma unroll
            for (int dx = 0; dx < 7; ++dx)
                wi[slot][dx] = sI[m][tx + dx];
            float b0 = sP[m][tx],     b1 = sP[m][tx + 1], b2 = sP[m][tx + 2],
                  b3 = sP[m][tx + 3], b4 = sP[m][tx + 4], b5 = sP[m][tx + 5],
                  b6 = sP[m][tx + 6];
            hlr[slot] = (v2){(b0 + b1) + (b2 + b3), (b3 + b4) + (b5 + b6)};
            cc[slot] = b3;
        }
    }
}

extern "C" void kernel_launch(void* const* d_in, const int* in_sizes, int n_in,
                              void* d_out, int out_size, void* d_ws, size_t ws_size,
                              hipStream_t stream) {
    const float* im0 = (const float*)d_in[0];
    const float* pe0 = (const float*)d_in[1];
    float* out = (float*)d_out;

    const size_t npix = (size_t)NIMG * HH * WW;   // 3,145,728
    float* imA = (float*)d_ws;                    // 12.6 MB
    float* imB = imA + npix;                      // 12.6 MB
    float* peA = imB + npix;                      // 12.6 MB (ws total 37.7 MB)
    float* peB = out;  // d_out doubles as the second pert buffer; iteration
                       // parity lands the final (iter-5) pert write in d_out.

    dim3 grid(WW / TW, HH / TH, NIMG);            // 8 x 32 x 12 = 3072 blocks
    dim3 block(256);

    swf_step<<<grid, block, 0, stream>>>(im0, pe0, imA, peA);  // iter 0
    swf_step<<<grid, block, 0, stream>>>(imA, peA, imB, peB);  // iter 1
    swf_step<<<grid, block, 0, stream>>>(imB, peB, imA, peA);  // iter 2
    swf_step<<<grid, block, 0, stream>>>(imA, peA, imB, peB);  // iter 3
    swf_step<<<grid, block, 0, stream>>>(imB, peB, imA, peA);  // iter 4
    swf_step<<<grid, block, 0, stream>>>(imA, peA, imB, out);  // iter 5
}